// Round 11
// baseline (341.885 us; speedup 1.0000x reference)
//
#include <hip/hip_runtime.h>
#include <hip/hip_cooperative_groups.h>

namespace cg = cooperative_groups;

// Problem constants (match reference)
constexpr int N_NODES = 10000;
constexpr int E_EDGES = 320000;
constexpr int G_GRAPHS = 256;
constexpr int IN_F = 128;
constexpr int H_F = 256;
constexpr int FP_F = 5000;
constexpr int OUT_F = 138;
constexpr int KCAT = H_F + FP_F;  // 5256
constexpr int KPAD = 5376;        // 42 * 128 (zero-padded for MFMA)
constexpr int KZ = 21;            // split-K chunks of 256; z=0 handled in fin
constexpr int DMAX = 128;         // padded adjacency slots (deg ~Poisson(32); >12 sigma)

// phase partition sizes
constexpr int ZB = (N_NODES + 255) / 256;            // 40
constexpr int W1TB = H_F * IN_F / 256;               // 128
constexpr int W2TB = H_F * H_F / 256;                // 256
constexpr int FPB = G_GRAPHS * (KPAD - H_F) / 8 / 256;  // 640 (x8-vectorized cast)
constexpr int GB = 157 * 4;                          // 628 gemm tiles
constexpr int HB = (E_EDGES + 255) / 256;            // 1250
constexpr int WT_TILES = (KPAD / 64) * (H_F / 64);   // 336
constexpr int M1B = (KZ - 1) * 16;                   // 320 mlp1 tiles
constexpr int AB = N_NODES / 4;                      // 2500 agg works

constexpr int N0 = ZB + W1TB + W2TB + FPB;           // 1064
constexpr int N1 = GB + HB + WT_TILES;               // 2214
constexpr int N2 = AB;                               // 2500
constexpr int N3 = GB + M1B;                         // 948
constexpr int N4 = AB;                               // 2500
constexpr int N5 = G_GRAPHS;                         // 256

typedef __attribute__((ext_vector_type(8))) short short8;   // 8 bf16
typedef __attribute__((ext_vector_type(4))) float f32x4;    // MFMA acc

struct Params {
    const float* x; const int* ei; const int* batch; const float* gfp;
    const float* W1; const float* b1; const float* W2; const float* b2;
    const float* Wm1; const float* bm1; const float* Wm2; const float* bm2;
    float* out;
    unsigned short* W1t; unsigned short* W2t; unsigned short* Abf;
    unsigned short* h1; unsigned short* hcat; unsigned short* Wm1t;
    float* partial; int* cnt; int* srcs_pad;
};

static __device__ __forceinline__ unsigned short f2bf(float f) {
    union { float f; unsigned u; } a; a.f = f;
    unsigned r = a.u + 0x7fffu + ((a.u >> 16) & 1u);  // RNE
    return (unsigned short)(r >> 16);
}
static __device__ __forceinline__ float bf2f(unsigned short u) {
    union { unsigned u; float f; } a; a.u = ((unsigned)u) << 16;
    return a.f;
}

// ---------------- shared MFMA GEMM tile body (64x64 tile, 4 waves, KB=128, T2 swizzle) ----
template <int K, bool AF32>
__device__ __forceinline__ void gemm_tile(unsigned short* a_lds, unsigned short* w_lds,
                                          const void* __restrict__ Asrc,
                                          const unsigned short* __restrict__ Wt,
                                          unsigned short* __restrict__ C,
                                          int bm0, int bn0, int tid) {
    constexpr int KB = 128;
    const int lane = tid & 63;
    const int wv = tid >> 6;

    f32x4 acc[4] = {};
    const int rA = wv * 16 + (lane & 15);
    const int kq = (lane >> 4) * 8;

    for (int kb = 0; kb < K; kb += KB) {
        for (int c = tid; c < 64 * KB / 8; c += 256) {
            int r = c >> 4;
            int k = (c & 15) * 8;
            int gr = bm0 + r;
            short8 v = {};
            if (gr < N_NODES) {
                if (AF32) {
                    const float* A = (const float*)Asrc;
                    const float* p = A + (size_t)gr * K + kb + k;
                    float4 lo = *reinterpret_cast<const float4*>(p);
                    float4 hi = *reinterpret_cast<const float4*>(p + 4);
                    v[0] = (short)f2bf(lo.x); v[1] = (short)f2bf(lo.y);
                    v[2] = (short)f2bf(lo.z); v[3] = (short)f2bf(lo.w);
                    v[4] = (short)f2bf(hi.x); v[5] = (short)f2bf(hi.y);
                    v[6] = (short)f2bf(hi.z); v[7] = (short)f2bf(hi.w);
                } else {
                    const unsigned short* A = (const unsigned short*)Asrc;
                    v = *reinterpret_cast<const short8*>(A + (size_t)gr * K + kb + k);
                }
            }
            int byte = r * (2 * KB) + ((2 * k) ^ ((r & 7) << 4));
            *reinterpret_cast<short8*>((char*)a_lds + byte) = v;
        }
        for (int c = tid; c < 64 * KB / 8; c += 256) {
            int r = c >> 4;
            int k = (c & 15) * 8;
            short8 v = *reinterpret_cast<const short8*>(Wt + (size_t)(bn0 + r) * K + kb + k);
            int byte = r * (2 * KB) + ((2 * k) ^ ((r & 7) << 4));
            *reinterpret_cast<short8*>((char*)w_lds + byte) = v;
        }
        __syncthreads();
#pragma unroll
        for (int t = 0; t < KB / 32; ++t) {
            const int k0 = t * 32 + kq;
            short8 af = *reinterpret_cast<const short8*>(
                (char*)a_lds + rA * (2 * KB) + ((2 * k0) ^ ((rA & 7) << 4)));
#pragma unroll
            for (int nt = 0; nt < 4; ++nt) {
                const int rW = nt * 16 + (lane & 15);
                short8 bfr = *reinterpret_cast<const short8*>(
                    (char*)w_lds + rW * (2 * KB) + ((2 * k0) ^ ((rW & 7) << 4)));
                acc[nt] = __builtin_amdgcn_mfma_f32_16x16x32_bf16(bfr, af, acc[nt], 0, 0, 0);
            }
        }
        __syncthreads();
    }

    const int row = bm0 + wv * 16 + (lane & 15);
    if (row < N_NODES) {
#pragma unroll
        for (int nt = 0; nt < 4; ++nt) {
            int col = bn0 + nt * 16 + (lane >> 4) * 4;
            ushort4 o;
            o.x = f2bf(acc[nt][0]);
            o.y = f2bf(acc[nt][1]);
            o.z = f2bf(acc[nt][2]);
            o.w = f2bf(acc[nt][3]);
            *reinterpret_cast<ushort4*>(C + (size_t)row * H_F + col) = o;
        }
    }
}

// ---------------- MLP1 split-K tile body (kz0..kz0+256), fp32 partial out ----------------
__device__ __forceinline__ void mlp1_tile(unsigned short* a_lds, unsigned short* w_lds,
                                          const unsigned short* __restrict__ hcat,
                                          const unsigned short* __restrict__ Wt,
                                          float* __restrict__ pz,
                                          int bm0, int bn0, int kz0, int tid) {
    constexpr int KB = 128;
    const int lane = tid & 63;
    const int wv = tid >> 6;

    f32x4 acc[4] = {};
    const int rA = wv * 16 + (lane & 15);
    const int kq = (lane >> 4) * 8;

    for (int kb = kz0; kb < kz0 + 256; kb += KB) {
        for (int c = tid; c < 64 * KB / 8; c += 256) {
            int r = c >> 4;
            int k = (c & 15) * 8;
            short8 v = *reinterpret_cast<const short8*>(hcat + (size_t)(bm0 + r) * KPAD + kb + k);
            int byte = r * (2 * KB) + ((2 * k) ^ ((r & 7) << 4));
            *reinterpret_cast<short8*>((char*)a_lds + byte) = v;
        }
        for (int c = tid; c < 64 * KB / 8; c += 256) {
            int r = c >> 4;
            int k = (c & 15) * 8;
            short8 v = *reinterpret_cast<const short8*>(Wt + (size_t)(bn0 + r) * KPAD + kb + k);
            int byte = r * (2 * KB) + ((2 * k) ^ ((r & 7) << 4));
            *reinterpret_cast<short8*>((char*)w_lds + byte) = v;
        }
        __syncthreads();
#pragma unroll
        for (int t = 0; t < KB / 32; ++t) {
            const int k0 = t * 32 + kq;
            short8 af = *reinterpret_cast<const short8*>(
                (char*)a_lds + rA * (2 * KB) + ((2 * k0) ^ ((rA & 7) << 4)));
#pragma unroll
            for (int nt = 0; nt < 4; ++nt) {
                const int rW = nt * 16 + (lane & 15);
                short8 bfr = *reinterpret_cast<const short8*>(
                    (char*)w_lds + rW * (2 * KB) + ((2 * k0) ^ ((rW & 7) << 4)));
                acc[nt] = __builtin_amdgcn_mfma_f32_16x16x32_bf16(bfr, af, acc[nt], 0, 0, 0);
            }
        }
        __syncthreads();
    }

    const int row = bm0 + wv * 16 + (lane & 15);
#pragma unroll
    for (int nt = 0; nt < 4; ++nt) {
        int col = bn0 + nt * 16 + (lane >> 4) * 4;
        float4 o; o.x = acc[nt][0]; o.y = acc[nt][1]; o.z = acc[nt][2]; o.w = acc[nt][3];
        *reinterpret_cast<float4*>(pz + (size_t)row * H_F + col) = o;
    }
}

// ---------------- GCN aggregation body: 1 node/WAVE, scalar edge loads, ILP-8 ----------------
__device__ __forceinline__ void agg_body(const unsigned short* __restrict__ hw,
                                         const int* __restrict__ cnt,
                                         const int* __restrict__ srcs_pad,
                                         const float* __restrict__ b,
                                         unsigned short* __restrict__ outp,
                                         int node_base, int tid) {
    const int lane = tid & 63;
    const int node = __builtin_amdgcn_readfirstlane(node_base + (tid >> 6));
    const float dd = rsqrtf((float)cnt[node] + 1.0f);
    const unsigned short* rowb = hw + lane * 4;
    const int* sp = srcs_pad + (node << 7);

    float a0, a1, a2, a3;
    {
        const ushort4 sv = *reinterpret_cast<const ushort4*>(hw + (size_t)node * H_F + lane * 4);
        const float4 bv = *reinterpret_cast<const float4*>(b + lane * 4);
        const float ddsq = dd * dd;
        a0 = bf2f(sv.x) * ddsq + bv.x;
        a1 = bf2f(sv.y) * ddsq + bv.y;
        a2 = bf2f(sv.z) * ddsq + bv.z;
        a3 = bf2f(sv.w) * ddsq + bv.w;
    }

    const int e1 = __builtin_amdgcn_readfirstlane(min(cnt[node], DMAX));
    int e = 0;
    for (; e + 8 <= e1; e += 8) {
        ushort4 v[8];
        float w[8];
#pragma unroll
        for (int q = 0; q < 8; ++q) {
            const int s = sp[e + q];                         // uniform -> s_load
            w[q] = rsqrtf((float)cnt[s] + 1.0f) * dd;        // uniform cnt -> s_load
            v[q] = *reinterpret_cast<const ushort4*>(rowb + (size_t)s * H_F);
        }
#pragma unroll
        for (int q = 0; q < 8; ++q) {
            a0 += bf2f(v[q].x) * w[q];
            a1 += bf2f(v[q].y) * w[q];
            a2 += bf2f(v[q].z) * w[q];
            a3 += bf2f(v[q].w) * w[q];
        }
    }
    for (; e < e1; ++e) {
        const int s = sp[e];
        const float w = rsqrtf((float)cnt[s] + 1.0f) * dd;
        const ushort4 v = *reinterpret_cast<const ushort4*>(rowb + (size_t)s * H_F);
        a0 += bf2f(v.x) * w;
        a1 += bf2f(v.y) * w;
        a2 += bf2f(v.z) * w;
        a3 += bf2f(v.w) * w;
    }
    ushort4 o;
    o.x = f2bf(fmaxf(a0, 0.0f));
    o.y = f2bf(fmaxf(a1, 0.0f));
    o.z = f2bf(fmaxf(a2, 0.0f));
    o.w = f2bf(fmaxf(a3, 0.0f));
    *reinterpret_cast<ushort4*>(outp + (size_t)node * H_F + lane * 4) = o;
}

// ---------------- phase work bodies ----------------
// P0: zero cnt | W1t | W2t | gfp->hcat (x8 vectorized)
__device__ __forceinline__ void work0(const Params& p, int w, int tid) {
    if (w < ZB) {
        int i = w * 256 + tid;
        if (i < N_NODES) p.cnt[i] = 0;
        return;
    }
    w -= ZB;
    if (w < W1TB) {
        int i = w * 256 + tid;               // < 32768 exactly
        int c = i >> 7, k = i & 127;
        p.W1t[i] = f2bf(p.W1[(size_t)k * H_F + c]);
        return;
    }
    w -= W1TB;
    if (w < W2TB) {
        int i = w * 256 + tid;               // < 65536 exactly
        int c = i >> 8, k = i & 255;
        p.W2t[i] = f2bf(p.W2[(size_t)k * H_F + c]);
        return;
    }
    w -= W2TB;
    {
        int idx = w * 256 + tid;             // 0..163839
        int g = idx / 640, k = (idx - g * 640) * 8;
        short8 v = {};
        if (k < FP_F) {                      // FP_F = 5000 = 625*8, aligned
            const float* src = p.gfp + (size_t)g * FP_F + k;
            float4 lo = *reinterpret_cast<const float4*>(src);
            float4 hi = *reinterpret_cast<const float4*>(src + 4);
            v[0] = (short)f2bf(lo.x); v[1] = (short)f2bf(lo.y);
            v[2] = (short)f2bf(lo.z); v[3] = (short)f2bf(lo.w);
            v[4] = (short)f2bf(hi.x); v[5] = (short)f2bf(hi.y);
            v[6] = (short)f2bf(hi.z); v[7] = (short)f2bf(hi.w);
        }
        *reinterpret_cast<short8*>(p.hcat + (size_t)g * KPAD + H_F + k) = v;
    }
}

// P1: gemm1 | fill padded adjacency | Wm1 transpose
__device__ __forceinline__ void work1(const Params& p, int w, int tid,
                                      unsigned short* a_lds, unsigned short* w_lds) {
    if (w < GB) {
        gemm_tile<IN_F, true>(a_lds, w_lds, p.x, p.W1t, p.Abf, (w % 157) * 64, (w / 157) * 64,
                              tid);
        return;
    }
    w -= GB;
    if (w < HB) {
        int e = w * 256 + tid;
        if (e < E_EDGES) {
            int s = p.ei[e];
            int d = p.ei[E_EDGES + e];
            int pos = atomicAdd(&p.cnt[d], 1);
            if (pos < DMAX) p.srcs_pad[(d << 7) + pos] = s;
        }
        return;
    }
    w -= HB;
    float* tbuf = (float*)a_lds;  // 64*65 fp32 = 16.6 KB, fits in a_lds+pad of 32 KB block
    const int k0 = (w % (KPAD / 64)) * 64;
    const int c0 = (w / (KPAD / 64)) * 64;
    for (int idx = tid; idx < 64 * 64; idx += 256) {
        int r = idx >> 6, cc = idx & 63;
        int k = k0 + r;
        tbuf[r * 65 + cc] = (k < KCAT) ? p.Wm1[(size_t)k * H_F + c0 + cc] : 0.0f;
    }
    __syncthreads();
    for (int idx = tid; idx < 64 * 64; idx += 256) {
        int r = idx >> 6, kk = idx & 63;
        p.Wm1t[(size_t)(c0 + r) * KPAD + k0 + kk] = f2bf(tbuf[kk * 65 + r]);
    }
    __syncthreads();  // protect tbuf across grid-stride iterations
}

// P3: gemm2 | mlp1 z>=1 tiles
__device__ __forceinline__ void work3(const Params& p, int w, int tid,
                                      unsigned short* a_lds, unsigned short* w_lds) {
    if (w < GB) {
        gemm_tile<H_F, false>(a_lds, w_lds, p.h1, p.W2t, p.Abf, (w % 157) * 64,
                              (w / 157) * 64, tid);
        return;
    }
    w -= GB;
    const int z = w / 16 + 1;
    const int r = w % 16;
    mlp1_tile(a_lds, w_lds, p.hcat, p.Wm1t, p.partial + (size_t)(z - 1) * (G_GRAPHS * H_F),
              (r & 3) * 64, (r >> 2) * 64, z * 256, tid);
}

// P5: fin = pool + mlp1 z0 + reduce + relu + mlp2 GEMV
__device__ __forceinline__ void work5(const Params& p, int g, int tid,
                                      unsigned short* a_lds, unsigned short* w_lds) {
    float* hrow = (float*)a_lds;  // 256 f32
    float* m = (float*)w_lds;     // 256 f32
    const int j = tid;
    int lo = 0, hi = N_NODES;
    while (lo < hi) { int mm = (lo + hi) >> 1; if (p.batch[mm] < g) lo = mm + 1; else hi = mm; }
    const int s = lo;
    lo = s; hi = N_NODES;
    while (lo < hi) { int mm = (lo + hi) >> 1; if (p.batch[mm] < g + 1) lo = mm + 1; else hi = mm; }
    const int e = lo;
    float c0 = 0.0f, c1 = 0.0f, c2 = 0.0f, c3 = 0.0f;
    int i = s;
    for (; i + 4 <= e; i += 4) {
        c0 += bf2f(p.h1[(size_t)(i + 0) * H_F + j]);
        c1 += bf2f(p.h1[(size_t)(i + 1) * H_F + j]);
        c2 += bf2f(p.h1[(size_t)(i + 2) * H_F + j]);
        c3 += bf2f(p.h1[(size_t)(i + 3) * H_F + j]);
    }
    for (; i < e; ++i) c0 += bf2f(p.h1[(size_t)i * H_F + j]);
    hrow[j] = ((c0 + c1) + (c2 + c3)) / fmaxf((float)(e - s), 1.0f);
    __syncthreads();

    float acc = p.bm1[j];
    for (int k = 0; k < H_F; k += 8) {
        short8 wv = *reinterpret_cast<const short8*>(p.Wm1t + (size_t)j * KPAD + k);
#pragma unroll
        for (int q = 0; q < 8; ++q) acc += hrow[k + q] * bf2f((unsigned short)wv[q]);
    }
    for (int z = 0; z < KZ - 1; ++z)
        acc += p.partial[((size_t)z * G_GRAPHS + g) * H_F + j];
    m[j] = fmaxf(acc, 0.0f);
    __syncthreads();
    if (j < OUT_F) {
        float a = p.bm2[j];
        for (int k = 0; k < H_F; ++k) a += m[k] * p.Wm2[k * OUT_F + j];
        p.out[g * OUT_F + j] = a;
    }
    __syncthreads();
}

// ---------------- cooperative mega-kernel: 6 phases, grid.sync between ----------------
__global__ __launch_bounds__(256) void mega(Params p) {
    __shared__ unsigned short a_lds[64 * 128];
    __shared__ unsigned short w_lds[64 * 128];
    cg::grid_group grid = cg::this_grid();
    const int tid = threadIdx.x;
    const int nb = gridDim.x;

    for (int w = blockIdx.x; w < N0; w += nb) work0(p, w, tid);
    grid.sync();
    for (int w = blockIdx.x; w < N1; w += nb) work1(p, w, tid, a_lds, w_lds);
    grid.sync();
    for (int w = blockIdx.x; w < N2; w += nb) agg_body(p.Abf, p.cnt, p.srcs_pad, p.b1, p.h1, w * 4, tid);
    grid.sync();
    for (int w = blockIdx.x; w < N3; w += nb) work3(p, w, tid, a_lds, w_lds);
    grid.sync();
    for (int w = blockIdx.x; w < N4; w += nb) agg_body(p.Abf, p.cnt, p.srcs_pad, p.b2, p.h1, w * 4, tid);
    grid.sync();
    for (int w = blockIdx.x; w < N5; w += nb) work5(p, w, tid, a_lds, w_lds);
}

// ---------------- fallback: same phases as separate launches ----------------
__global__ __launch_bounds__(256) void k_phase(Params p, int ph) {
    __shared__ unsigned short a_lds[64 * 128];
    __shared__ unsigned short w_lds[64 * 128];
    const int tid = threadIdx.x;
    const int w = blockIdx.x;
    switch (ph) {
        case 0: work0(p, w, tid); break;
        case 1: work1(p, w, tid, a_lds, w_lds); break;
        case 2: agg_body(p.Abf, p.cnt, p.srcs_pad, p.b1, p.h1, w * 4, tid); break;
        case 3: work3(p, w, tid, a_lds, w_lds); break;
        case 4: agg_body(p.Abf, p.cnt, p.srcs_pad, p.b2, p.h1, w * 4, tid); break;
        case 5: work5(p, w, tid, a_lds, w_lds); break;
    }
}

extern "C" void kernel_launch(void* const* d_in, const int* in_sizes, int n_in,
                              void* d_out, int out_size, void* d_ws, size_t ws_size,
                              hipStream_t stream) {
    Params p;
    p.x    = (const float*)d_in[0];
    p.ei   = (const int*)d_in[1];
    p.batch= (const int*)d_in[2];
    p.gfp  = (const float*)d_in[3];
    p.W1   = (const float*)d_in[4];
    p.b1   = (const float*)d_in[5];
    p.W2   = (const float*)d_in[6];
    p.b2   = (const float*)d_in[7];
    p.Wm1  = (const float*)d_in[8];
    p.bm1  = (const float*)d_in[9];
    p.Wm2  = (const float*)d_in[10];
    p.bm2  = (const float*)d_in[11];
    p.out  = (float*)d_out;

    p.W1t  = (unsigned short*)d_ws;                            // IN*H bf16
    p.W2t  = p.W1t + IN_F * H_F;                               // H*H bf16
    p.Abf  = p.W2t + H_F * H_F;                                // N*H bf16
    p.h1   = p.Abf + (size_t)N_NODES * H_F;                    // N*H bf16
    p.hcat = p.h1 + (size_t)N_NODES * H_F;                     // G*KPAD bf16
    p.Wm1t = p.hcat + (size_t)G_GRAPHS * KPAD;                 // H*KPAD bf16
    p.partial = (float*)(p.Wm1t + (size_t)H_F * KPAD);         // (KZ-1)*G*H f32
    p.cnt  = (int*)(p.partial + (size_t)(KZ - 1) * G_GRAPHS * H_F);  // N
    p.srcs_pad = p.cnt + N_NODES;                              // N*DMAX

    // cooperative single-launch: grid sized by occupancy (LDS 32KB -> 5 blocks/CU)
    int occ = 0;
    if (hipOccupancyMaxActiveBlocksPerMultiprocessor(&occ, (const void*)mega, 256, 0) !=
            hipSuccess || occ <= 0)
        occ = 4;
    if (occ > 5) occ = 5;
    int nblk = occ * 256;

    void* kargs[] = { (void*)&p };
    hipError_t le = hipLaunchCooperativeKernel((const void*)mega, dim3(nblk), dim3(256),
                                               kargs, 0, stream);
    if (le != hipSuccess) {
        // deterministic fallback: same phase bodies as separate launches
        k_phase<<<N0, 256, 0, stream>>>(p, 0);
        k_phase<<<N1, 256, 0, stream>>>(p, 1);
        k_phase<<<N2, 256, 0, stream>>>(p, 2);
        k_phase<<<N3, 256, 0, stream>>>(p, 3);
        k_phase<<<N4, 256, 0, stream>>>(p, 4);
        k_phase<<<N5, 256, 0, stream>>>(p, 5);
    }
}

// Round 12
// 117.829 us; speedup vs baseline: 2.9015x; 2.9015x over previous
//
#include <hip/hip_runtime.h>

// Problem constants (match reference)
constexpr int N_NODES = 10000;
constexpr int E_EDGES = 320000;
constexpr int G_GRAPHS = 256;
constexpr int IN_F = 128;
constexpr int H_F = 256;
constexpr int FP_F = 5000;
constexpr int OUT_F = 138;
constexpr int KCAT = H_F + FP_F;  // 5256
constexpr int KPAD = 5376;        // 42 * 128 (zero-padded for MFMA)
constexpr int KZ = 21;            // split-K chunks of 256; z=0 handled in k_fin
constexpr int DMAX = 128;         // padded adjacency slots (deg ~Poisson(32); >12 sigma)

// fused-launch partition sizes
constexpr int ZB = (N_NODES + 255) / 256;            // 40
constexpr int W1TB = H_F * IN_F / 256;               // 128
constexpr int W2TB = H_F * H_F / 256;                // 256
constexpr int FPB = G_GRAPHS * (KPAD - H_F) / 8 / 256;  // 640 (x8-vectorized cast)
constexpr int HB = (E_EDGES + 255) / 256;            // 1250
constexpr int WT_TILES = (KPAD / 64) * (H_F / 64);   // 336
constexpr int GB = 157 * 4;                          // 628 gemm tiles
constexpr int M1H = 160;                             // half of the 320 mlp1 tiles
constexpr int AB = N_NODES / 4;                      // 2500 agg blocks

typedef __attribute__((ext_vector_type(8))) short short8;   // 8 bf16
typedef __attribute__((ext_vector_type(4))) float f32x4;    // MFMA acc

static __device__ __forceinline__ unsigned short f2bf(float f) {
    union { float f; unsigned u; } a; a.f = f;
    unsigned r = a.u + 0x7fffu + ((a.u >> 16) & 1u);  // RNE
    return (unsigned short)(r >> 16);
}
static __device__ __forceinline__ float bf2f(unsigned short u) {
    union { unsigned u; float f; } a; a.u = ((unsigned)u) << 16;
    return a.f;
}

// ---------------- shared MFMA GEMM tile body ----------------
// 64x64 tile, 4 waves, KB=128 LDS chunks, XOR-swizzled (T2).
// mfma(B_frag, A_frag) computes C^T so reg index walks C columns -> packed stores.
template <int K, bool AF32>
__device__ __forceinline__ void gemm_tile(unsigned short* a_lds, unsigned short* w_lds,
                                          const void* __restrict__ Asrc,
                                          const unsigned short* __restrict__ Wt,
                                          unsigned short* __restrict__ C,
                                          int bm0, int bn0, int tid) {
    constexpr int KB = 128;
    const int lane = tid & 63;
    const int wv = tid >> 6;

    f32x4 acc[4] = {};
    const int rA = wv * 16 + (lane & 15);
    const int kq = (lane >> 4) * 8;

    for (int kb = 0; kb < K; kb += KB) {
        for (int c = tid; c < 64 * KB / 8; c += 256) {
            int r = c >> 4;
            int k = (c & 15) * 8;
            int gr = bm0 + r;
            short8 v = {};
            if (gr < N_NODES) {
                if (AF32) {
                    const float* A = (const float*)Asrc;
                    const float* p = A + (size_t)gr * K + kb + k;
                    float4 lo = *reinterpret_cast<const float4*>(p);
                    float4 hi = *reinterpret_cast<const float4*>(p + 4);
                    v[0] = (short)f2bf(lo.x); v[1] = (short)f2bf(lo.y);
                    v[2] = (short)f2bf(lo.z); v[3] = (short)f2bf(lo.w);
                    v[4] = (short)f2bf(hi.x); v[5] = (short)f2bf(hi.y);
                    v[6] = (short)f2bf(hi.z); v[7] = (short)f2bf(hi.w);
                } else {
                    const unsigned short* A = (const unsigned short*)Asrc;
                    v = *reinterpret_cast<const short8*>(A + (size_t)gr * K + kb + k);
                }
            }
            int byte = r * (2 * KB) + ((2 * k) ^ ((r & 7) << 4));
            *reinterpret_cast<short8*>((char*)a_lds + byte) = v;
        }
        for (int c = tid; c < 64 * KB / 8; c += 256) {
            int r = c >> 4;
            int k = (c & 15) * 8;
            short8 v = *reinterpret_cast<const short8*>(Wt + (size_t)(bn0 + r) * K + kb + k);
            int byte = r * (2 * KB) + ((2 * k) ^ ((r & 7) << 4));
            *reinterpret_cast<short8*>((char*)w_lds + byte) = v;
        }
        __syncthreads();
#pragma unroll
        for (int t = 0; t < KB / 32; ++t) {
            const int k0 = t * 32 + kq;
            short8 af = *reinterpret_cast<const short8*>(
                (char*)a_lds + rA * (2 * KB) + ((2 * k0) ^ ((rA & 7) << 4)));
#pragma unroll
            for (int nt = 0; nt < 4; ++nt) {
                const int rW = nt * 16 + (lane & 15);
                short8 bfr = *reinterpret_cast<const short8*>(
                    (char*)w_lds + rW * (2 * KB) + ((2 * k0) ^ ((rW & 7) << 4)));
                acc[nt] = __builtin_amdgcn_mfma_f32_16x16x32_bf16(bfr, af, acc[nt], 0, 0, 0);
            }
        }
        __syncthreads();
    }

    const int row = bm0 + wv * 16 + (lane & 15);
    if (row < N_NODES) {
#pragma unroll
        for (int nt = 0; nt < 4; ++nt) {
            int col = bn0 + nt * 16 + (lane >> 4) * 4;
            ushort4 o;
            o.x = f2bf(acc[nt][0]);
            o.y = f2bf(acc[nt][1]);
            o.z = f2bf(acc[nt][2]);
            o.w = f2bf(acc[nt][3]);
            *reinterpret_cast<ushort4*>(C + (size_t)row * H_F + col) = o;
        }
    }
}

// ---------------- MLP1 split-K tile body (kz0..kz0+256), fp32 partial out ----------------
__device__ __forceinline__ void mlp1_tile(unsigned short* a_lds, unsigned short* w_lds,
                                          const unsigned short* __restrict__ hcat,
                                          const unsigned short* __restrict__ Wt,
                                          float* __restrict__ pz,
                                          int bm0, int bn0, int kz0, int tid) {
    constexpr int KB = 128;
    const int lane = tid & 63;
    const int wv = tid >> 6;

    f32x4 acc[4] = {};
    const int rA = wv * 16 + (lane & 15);
    const int kq = (lane >> 4) * 8;

    for (int kb = kz0; kb < kz0 + 256; kb += KB) {
        for (int c = tid; c < 64 * KB / 8; c += 256) {
            int r = c >> 4;
            int k = (c & 15) * 8;
            short8 v = *reinterpret_cast<const short8*>(hcat + (size_t)(bm0 + r) * KPAD + kb + k);
            int byte = r * (2 * KB) + ((2 * k) ^ ((r & 7) << 4));
            *reinterpret_cast<short8*>((char*)a_lds + byte) = v;
        }
        for (int c = tid; c < 64 * KB / 8; c += 256) {
            int r = c >> 4;
            int k = (c & 15) * 8;
            short8 v = *reinterpret_cast<const short8*>(Wt + (size_t)(bn0 + r) * KPAD + kb + k);
            int byte = r * (2 * KB) + ((2 * k) ^ ((r & 7) << 4));
            *reinterpret_cast<short8*>((char*)w_lds + byte) = v;
        }
        __syncthreads();
#pragma unroll
        for (int t = 0; t < KB / 32; ++t) {
            const int k0 = t * 32 + kq;
            short8 af = *reinterpret_cast<const short8*>(
                (char*)a_lds + rA * (2 * KB) + ((2 * k0) ^ ((rA & 7) << 4)));
#pragma unroll
            for (int nt = 0; nt < 4; ++nt) {
                const int rW = nt * 16 + (lane & 15);
                short8 bfr = *reinterpret_cast<const short8*>(
                    (char*)w_lds + rW * (2 * KB) + ((2 * k0) ^ ((rW & 7) << 4)));
                acc[nt] = __builtin_amdgcn_mfma_f32_16x16x32_bf16(bfr, af, acc[nt], 0, 0, 0);
            }
        }
        __syncthreads();
    }

    const int row = bm0 + wv * 16 + (lane & 15);
#pragma unroll
    for (int nt = 0; nt < 4; ++nt) {
        int col = bn0 + nt * 16 + (lane >> 4) * 4;
        float4 o; o.x = acc[nt][0]; o.y = acc[nt][1]; o.z = acc[nt][2]; o.w = acc[nt][3];
        *reinterpret_cast<float4*>(pz + (size_t)row * H_F + col) = o;
    }
}

// ---------------- GCN aggregation body: 1 node/WAVE, scalar edge loads, ILP-8 ----------------
// edge norm computed on the fly: rsqrt(cnt[s]+1)*rsqrt(cnt[d]+1) (no dinv buffer)
__device__ __forceinline__ void agg_body(const unsigned short* __restrict__ hw,
                                         const int* __restrict__ cnt,
                                         const int* __restrict__ srcs_pad,
                                         const float* __restrict__ b,
                                         unsigned short* __restrict__ outp,
                                         int node_base, int tid) {
    const int lane = tid & 63;
    const int node = __builtin_amdgcn_readfirstlane(node_base + (tid >> 6));
    const float dd = rsqrtf((float)cnt[node] + 1.0f);
    const unsigned short* rowb = hw + lane * 4;
    const int* sp = srcs_pad + (node << 7);

    float a0, a1, a2, a3;
    {
        const ushort4 sv = *reinterpret_cast<const ushort4*>(hw + (size_t)node * H_F + lane * 4);
        const float4 bv = *reinterpret_cast<const float4*>(b + lane * 4);
        const float ddsq = dd * dd;
        a0 = bf2f(sv.x) * ddsq + bv.x;
        a1 = bf2f(sv.y) * ddsq + bv.y;
        a2 = bf2f(sv.z) * ddsq + bv.z;
        a3 = bf2f(sv.w) * ddsq + bv.w;
    }

    const int e1 = __builtin_amdgcn_readfirstlane(min(cnt[node], DMAX));
    int e = 0;
    for (; e + 8 <= e1; e += 8) {
        ushort4 v[8];
        float w[8];
#pragma unroll
        for (int q = 0; q < 8; ++q) {
            const int s = sp[e + q];                         // uniform -> s_load
            w[q] = rsqrtf((float)cnt[s] + 1.0f) * dd;        // uniform cnt -> s_load
            v[q] = *reinterpret_cast<const ushort4*>(rowb + (size_t)s * H_F);
        }
#pragma unroll
        for (int q = 0; q < 8; ++q) {
            a0 += bf2f(v[q].x) * w[q];
            a1 += bf2f(v[q].y) * w[q];
            a2 += bf2f(v[q].z) * w[q];
            a3 += bf2f(v[q].w) * w[q];
        }
    }
    for (; e < e1; ++e) {
        const int s = sp[e];
        const float w = rsqrtf((float)cnt[s] + 1.0f) * dd;
        const ushort4 v = *reinterpret_cast<const ushort4*>(rowb + (size_t)s * H_F);
        a0 += bf2f(v.x) * w;
        a1 += bf2f(v.y) * w;
        a2 += bf2f(v.z) * w;
        a3 += bf2f(v.w) * w;
    }
    ushort4 o;
    o.x = f2bf(fmaxf(a0, 0.0f));
    o.y = f2bf(fmaxf(a1, 0.0f));
    o.z = f2bf(fmaxf(a2, 0.0f));
    o.w = f2bf(fmaxf(a3, 0.0f));
    *reinterpret_cast<ushort4*>(outp + (size_t)node * H_F + lane * 4) = o;
}

// ---------------- K1: [zero cnt | W1t | W2t | gfp->hcat (x8)] ----------------
__global__ void k_p1(const float* __restrict__ W1, const float* __restrict__ W2,
                     const float* __restrict__ gfp, int* __restrict__ cnt,
                     unsigned short* __restrict__ W1t, unsigned short* __restrict__ W2t,
                     unsigned short* __restrict__ hcat) {
    int w = blockIdx.x;
    if (w < ZB) {
        int i = w * 256 + threadIdx.x;
        if (i < N_NODES) cnt[i] = 0;
        return;
    }
    w -= ZB;
    if (w < W1TB) {
        int i = w * 256 + threadIdx.x;       // < 32768 exactly
        int c = i >> 7, k = i & 127;
        W1t[i] = f2bf(W1[(size_t)k * H_F + c]);
        return;
    }
    w -= W1TB;
    if (w < W2TB) {
        int i = w * 256 + threadIdx.x;       // < 65536 exactly
        int c = i >> 8, k = i & 255;
        W2t[i] = f2bf(W2[(size_t)k * H_F + c]);
        return;
    }
    w -= W2TB;
    {
        int idx = w * 256 + threadIdx.x;     // 0..163839
        int g = idx / 640, k = (idx - g * 640) * 8;
        short8 v = {};
        if (k < FP_F) {                      // FP_F = 5000 = 625*8, chunk-aligned
            const float* src = gfp + (size_t)g * FP_F + k;
            float4 lo = *reinterpret_cast<const float4*>(src);
            float4 hi = *reinterpret_cast<const float4*>(src + 4);
            v[0] = (short)f2bf(lo.x); v[1] = (short)f2bf(lo.y);
            v[2] = (short)f2bf(lo.z); v[3] = (short)f2bf(lo.w);
            v[4] = (short)f2bf(hi.x); v[5] = (short)f2bf(hi.y);
            v[6] = (short)f2bf(hi.z); v[7] = (short)f2bf(hi.w);
        }
        *reinterpret_cast<short8*>(hcat + (size_t)g * KPAD + H_F + k) = v;
    }
}

// ---------------- K2: [gemm1 tiles | fill padded adjacency | Wm1 transpose] ----------------
__global__ __launch_bounds__(256) void k_p2(const float* __restrict__ x,
                                            const unsigned short* __restrict__ W1t,
                                            unsigned short* __restrict__ Abf,
                                            const int* __restrict__ ei,
                                            int* __restrict__ cnt,
                                            int* __restrict__ srcs_pad,
                                            const float* __restrict__ Wm1,
                                            unsigned short* __restrict__ Wt) {
    __shared__ unsigned short a_lds[64 * 128];
    __shared__ unsigned short w_lds[64 * 128];
    int bx = blockIdx.x;
    if (bx < GB) {
        gemm_tile<IN_F, true>(a_lds, w_lds, x, W1t, Abf, (bx % 157) * 64, (bx / 157) * 64,
                              threadIdx.x);
        return;
    }
    bx -= GB;
    if (bx < HB) {
        int e = bx * 256 + threadIdx.x;
        if (e < E_EDGES) {
            int s = ei[e];
            int d = ei[E_EDGES + e];
            int p = atomicAdd(&cnt[d], 1);
            if (p < DMAX) srcs_pad[(d << 7) + p] = s;
        }
        return;
    }
    bx -= HB;
    // Wm1 transpose tile: fp32 [KCAT][256] -> bf16 [256][KPAD]; reuse a_lds as fp32 buf
    float* tbuf = (float*)a_lds;  // 64*65 floats = 16.6 KB < 32 KB of a_lds+w_lds
    const int k0 = (bx % (KPAD / 64)) * 64;
    const int c0 = (bx / (KPAD / 64)) * 64;
    for (int idx = threadIdx.x; idx < 64 * 64; idx += 256) {
        int r = idx >> 6, cc = idx & 63;  // r: k-offset
        int k = k0 + r;
        tbuf[r * 65 + cc] = (k < KCAT) ? Wm1[(size_t)k * H_F + c0 + cc] : 0.0f;
    }
    __syncthreads();
    for (int idx = threadIdx.x; idx < 64 * 64; idx += 256) {
        int r = idx >> 6, kk = idx & 63;  // r: c-offset
        Wt[(size_t)(c0 + r) * KPAD + k0 + kk] = f2bf(tbuf[kk * 65 + r]);
    }
}

// ---------------- K3: [agg layer 1 | mlp1 tiles z=1..10] ----------------
__global__ __launch_bounds__(256) void k_p3(const unsigned short* __restrict__ Abf,
                                            const int* __restrict__ cnt,
                                            const int* __restrict__ srcs_pad,
                                            const float* __restrict__ b1,
                                            unsigned short* __restrict__ h1,
                                            const unsigned short* __restrict__ hcat,
                                            const unsigned short* __restrict__ Wm1t,
                                            float* __restrict__ partial) {
    __shared__ unsigned short a_lds[64 * 128];
    __shared__ unsigned short w_lds[64 * 128];
    int bx = blockIdx.x;
    if (bx < AB) {
        agg_body(Abf, cnt, srcs_pad, b1, h1, bx * 4, threadIdx.x);
        return;
    }
    bx -= AB;  // 0..159: mlp1 tiles, z in [1, 11)
    const int z = bx / 16 + 1;
    const int r = bx % 16;
    mlp1_tile(a_lds, w_lds, hcat, Wm1t, partial + (size_t)(z - 1) * (G_GRAPHS * H_F),
              (r & 3) * 64, (r >> 2) * 64, z * 256, threadIdx.x);
}

// ---------------- K4: gemm2 ----------------
__global__ __launch_bounds__(256) void k_p4(const unsigned short* __restrict__ h1,
                                            const unsigned short* __restrict__ W2t,
                                            unsigned short* __restrict__ Abf) {
    __shared__ unsigned short a_lds[64 * 128];
    __shared__ unsigned short w_lds[64 * 128];
    gemm_tile<H_F, false>(a_lds, w_lds, h1, W2t, Abf, (blockIdx.x % 157) * 64,
                          (blockIdx.x / 157) * 64, threadIdx.x);
}

// ---------------- K5: [agg layer 2 | mlp1 tiles z=11..20] ----------------
__global__ __launch_bounds__(256) void k_p5(const unsigned short* __restrict__ Abf,
                                            const int* __restrict__ cnt,
                                            const int* __restrict__ srcs_pad,
                                            const float* __restrict__ b2,
                                            unsigned short* __restrict__ h1,
                                            const unsigned short* __restrict__ hcat,
                                            const unsigned short* __restrict__ Wm1t,
                                            float* __restrict__ partial) {
    __shared__ unsigned short a_lds[64 * 128];
    __shared__ unsigned short w_lds[64 * 128];
    int bx = blockIdx.x;
    if (bx < AB) {
        agg_body(Abf, cnt, srcs_pad, b2, h1, bx * 4, threadIdx.x);
        return;
    }
    bx -= AB;  // 0..159: mlp1 tiles, z in [11, 21)
    const int z = bx / 16 + 11;
    const int r = bx % 16;
    mlp1_tile(a_lds, w_lds, hcat, Wm1t, partial + (size_t)(z - 1) * (G_GRAPHS * H_F),
              (r & 3) * 64, (r >> 2) * 64, z * 256, threadIdx.x);
}

// ---------------- K6: fin = pool + mlp1 z0 + reduce + relu + mlp2 GEMV ----------------
__global__ void k_fin(const unsigned short* __restrict__ h1, const int* __restrict__ batch,
                      const unsigned short* __restrict__ Wm1t,
                      const float* __restrict__ partial, const float* __restrict__ bm1,
                      const float* __restrict__ Wm2, const float* __restrict__ bm2,
                      float* __restrict__ out) {
    __shared__ float m[H_F];
    __shared__ float hrow[H_F];
    const int g = blockIdx.x;
    const int j = threadIdx.x;
    // graph bounds (batch sorted)
    int lo = 0, hi = N_NODES;
    while (lo < hi) { int mm = (lo + hi) >> 1; if (batch[mm] < g) lo = mm + 1; else hi = mm; }
    const int s = lo;
    lo = s; hi = N_NODES;
    while (lo < hi) { int mm = (lo + hi) >> 1; if (batch[mm] < g + 1) lo = mm + 1; else hi = mm; }
    const int e = lo;
    // mean pool column j over rows [s, e)
    float c0 = 0.0f, c1 = 0.0f, c2 = 0.0f, c3 = 0.0f;
    int i = s;
    for (; i + 4 <= e; i += 4) {
        c0 += bf2f(h1[(size_t)(i + 0) * H_F + j]);
        c1 += bf2f(h1[(size_t)(i + 1) * H_F + j]);
        c2 += bf2f(h1[(size_t)(i + 2) * H_F + j]);
        c3 += bf2f(h1[(size_t)(i + 3) * H_F + j]);
    }
    for (; i < e; ++i) c0 += bf2f(h1[(size_t)i * H_F + j]);
    hrow[j] = ((c0 + c1) + (c2 + c3)) / fmaxf((float)(e - s), 1.0f);
    __syncthreads();

    float acc = bm1[j];
    // z=0 contribution: dot(hrow, Wm1t[j, 0:256])
    for (int k = 0; k < H_F; k += 8) {
        short8 wv = *reinterpret_cast<const short8*>(Wm1t + (size_t)j * KPAD + k);
#pragma unroll
        for (int q = 0; q < 8; ++q) acc += hrow[k + q] * bf2f((unsigned short)wv[q]);
    }
    for (int z = 0; z < KZ - 1; ++z)
        acc += partial[((size_t)z * G_GRAPHS + g) * H_F + j];
    m[j] = fmaxf(acc, 0.0f);
    __syncthreads();
    if (j < OUT_F) {
        float a = bm2[j];
        for (int k = 0; k < H_F; ++k) a += m[k] * Wm2[k * OUT_F + j];
        out[g * OUT_F + j] = a;
    }
}

extern "C" void kernel_launch(void* const* d_in, const int* in_sizes, int n_in,
                              void* d_out, int out_size, void* d_ws, size_t ws_size,
                              hipStream_t stream) {
    const float* x       = (const float*)d_in[0];   // [N, IN]
    const int*   ei      = (const int*)d_in[1];     // [2, E]
    const int*   batch   = (const int*)d_in[2];     // [N]
    const float* gfp     = (const float*)d_in[3];   // [G, FP]
    const float* W1      = (const float*)d_in[4];   // [IN, H]
    const float* b1      = (const float*)d_in[5];
    const float* W2      = (const float*)d_in[6];   // [H, H]
    const float* b2      = (const float*)d_in[7];
    const float* Wm1     = (const float*)d_in[8];   // [H+FP, H]
    const float* bm1     = (const float*)d_in[9];
    const float* Wm2     = (const float*)d_in[10];  // [H, OUT]
    const float* bm2     = (const float*)d_in[11];
    float* out = (float*)d_out;                     // [G, OUT]

    // workspace layout (no aliasing)
    unsigned short* W1t  = (unsigned short*)d_ws;              // IN*H bf16
    unsigned short* W2t  = W1t + IN_F * H_F;                   // H*H bf16
    unsigned short* Abf  = W2t + H_F * H_F;                    // N*H bf16
    unsigned short* h1   = Abf + (size_t)N_NODES * H_F;        // N*H bf16
    unsigned short* hcat = h1 + (size_t)N_NODES * H_F;         // G*KPAD bf16
    unsigned short* Wm1t = hcat + (size_t)G_GRAPHS * KPAD;     // H*KPAD bf16
    float* partial = (float*)(Wm1t + (size_t)H_F * KPAD);      // (KZ-1)*G*H f32
    int* cnt      = (int*)(partial + (size_t)(KZ - 1) * G_GRAPHS * H_F);  // N
    int* srcs_pad = cnt + N_NODES;                             // N*DMAX

    // K1: zero cnt | W1t | W2t | gfp->hcat (x8)
    k_p1<<<ZB + W1TB + W2TB + FPB, 256, 0, stream>>>(W1, W2, gfp, cnt, W1t, W2t, hcat);

    // K2: gemm1 | fill padded adjacency | Wm1 transpose
    k_p2<<<GB + HB + WT_TILES, 256, 0, stream>>>(x, W1t, Abf, ei, cnt, srcs_pad, Wm1, Wm1t);

    // K3: agg layer 1 | mlp1 z=1..10
    k_p3<<<AB + M1H, 256, 0, stream>>>(Abf, cnt, srcs_pad, b1, h1, hcat, Wm1t, partial);

    // K4: gemm2
    k_p4<<<GB, 256, 0, stream>>>(h1, W2t, Abf);

    // K5: agg layer 2 | mlp1 z=11..20
    k_p5<<<AB + M1H, 256, 0, stream>>>(Abf, cnt, srcs_pad, b2, h1, hcat, Wm1t, partial);

    // K6: fin (pool + mlp1 z0 + reduce + relu + mlp2)
    k_fin<<<G_GRAPHS, H_F, 0, stream>>>(h1, batch, Wm1t, partial, bm1, Wm2, bm2, out);
}

// Round 13
// 108.136 us; speedup vs baseline: 3.1616x; 1.0896x over previous
//
#include <hip/hip_runtime.h>

// Problem constants (match reference)
constexpr int N_NODES = 10000;
constexpr int E_EDGES = 320000;
constexpr int G_GRAPHS = 256;
constexpr int IN_F = 128;
constexpr int H_F = 256;
constexpr int FP_F = 5000;
constexpr int OUT_F = 138;
constexpr int KCAT = H_F + FP_F;  // 5256
constexpr int KPAD = 5376;        // 42 * 128 (zero-padded for MFMA)
constexpr int KZ = 21;            // split-K chunks of 256; z=0 handled in k_fin
constexpr int DMAX = 128;         // padded adjacency slots (deg ~Poisson(32); >12 sigma)

// fused-launch partition sizes
constexpr int ZB = (N_NODES + 255) / 256;            // 40
constexpr int W1TB = H_F * IN_F / 256;               // 128
constexpr int W2TB = H_F * H_F / 256;                // 256
constexpr int FPB = G_GRAPHS * (KPAD - H_F) / 8 / 256;  // 640 (x8-vectorized cast)
constexpr int HB = (E_EDGES + 255) / 256;            // 1250
constexpr int WT_TILES = (KPAD / 64) * (H_F / 64);   // 336
constexpr int GB = 157 * 4;                          // 628 gemm tiles
constexpr int M1B = (KZ - 1) * 16;                   // 320 mlp1 tiles
constexpr int AB = N_NODES / 4;                      // 2500 agg blocks

typedef __attribute__((ext_vector_type(8))) short short8;   // 8 bf16
typedef __attribute__((ext_vector_type(4))) float f32x4;    // MFMA acc

static __device__ __forceinline__ unsigned short f2bf(float f) {
    union { float f; unsigned u; } a; a.f = f;
    unsigned r = a.u + 0x7fffu + ((a.u >> 16) & 1u);  // RNE
    return (unsigned short)(r >> 16);
}
static __device__ __forceinline__ float bf2f(unsigned short u) {
    union { unsigned u; float f; } a; a.u = ((unsigned)u) << 16;
    return a.f;
}

// ---------------- shared MFMA GEMM tile body ----------------
// 64x64 tile, 4 waves, KB=128 LDS chunks, XOR-swizzled (T2).
// mfma(B_frag, A_frag) computes C^T so reg index walks C columns -> packed stores.
template <int K, bool AF32>
__device__ __forceinline__ void gemm_tile(unsigned short* a_lds, unsigned short* w_lds,
                                          const void* __restrict__ Asrc,
                                          const unsigned short* __restrict__ Wt,
                                          unsigned short* __restrict__ C,
                                          int bm0, int bn0, int tid) {
    constexpr int KB = 128;
    const int lane = tid & 63;
    const int wv = tid >> 6;

    f32x4 acc[4] = {};
    const int rA = wv * 16 + (lane & 15);
    const int kq = (lane >> 4) * 8;

    for (int kb = 0; kb < K; kb += KB) {
        for (int c = tid; c < 64 * KB / 8; c += 256) {
            int r = c >> 4;
            int k = (c & 15) * 8;
            int gr = bm0 + r;
            short8 v = {};
            if (gr < N_NODES) {
                if (AF32) {
                    const float* A = (const float*)Asrc;
                    const float* p = A + (size_t)gr * K + kb + k;
                    float4 lo = *reinterpret_cast<const float4*>(p);
                    float4 hi = *reinterpret_cast<const float4*>(p + 4);
                    v[0] = (short)f2bf(lo.x); v[1] = (short)f2bf(lo.y);
                    v[2] = (short)f2bf(lo.z); v[3] = (short)f2bf(lo.w);
                    v[4] = (short)f2bf(hi.x); v[5] = (short)f2bf(hi.y);
                    v[6] = (short)f2bf(hi.z); v[7] = (short)f2bf(hi.w);
                } else {
                    const unsigned short* A = (const unsigned short*)Asrc;
                    v = *reinterpret_cast<const short8*>(A + (size_t)gr * K + kb + k);
                }
            }
            int byte = r * (2 * KB) + ((2 * k) ^ ((r & 7) << 4));
            *reinterpret_cast<short8*>((char*)a_lds + byte) = v;
        }
        for (int c = tid; c < 64 * KB / 8; c += 256) {
            int r = c >> 4;
            int k = (c & 15) * 8;
            short8 v = *reinterpret_cast<const short8*>(Wt + (size_t)(bn0 + r) * K + kb + k);
            int byte = r * (2 * KB) + ((2 * k) ^ ((r & 7) << 4));
            *reinterpret_cast<short8*>((char*)w_lds + byte) = v;
        }
        __syncthreads();
#pragma unroll
        for (int t = 0; t < KB / 32; ++t) {
            const int k0 = t * 32 + kq;
            short8 af = *reinterpret_cast<const short8*>(
                (char*)a_lds + rA * (2 * KB) + ((2 * k0) ^ ((rA & 7) << 4)));
#pragma unroll
            for (int nt = 0; nt < 4; ++nt) {
                const int rW = nt * 16 + (lane & 15);
                short8 bfr = *reinterpret_cast<const short8*>(
                    (char*)w_lds + rW * (2 * KB) + ((2 * k0) ^ ((rW & 7) << 4)));
                acc[nt] = __builtin_amdgcn_mfma_f32_16x16x32_bf16(bfr, af, acc[nt], 0, 0, 0);
            }
        }
        __syncthreads();
    }

    const int row = bm0 + wv * 16 + (lane & 15);
    if (row < N_NODES) {
#pragma unroll
        for (int nt = 0; nt < 4; ++nt) {
            int col = bn0 + nt * 16 + (lane >> 4) * 4;
            ushort4 o;
            o.x = f2bf(acc[nt][0]);
            o.y = f2bf(acc[nt][1]);
            o.z = f2bf(acc[nt][2]);
            o.w = f2bf(acc[nt][3]);
            *reinterpret_cast<ushort4*>(C + (size_t)row * H_F + col) = o;
        }
    }
}

// ---------------- MLP1 split-K tile body (kz0..kz0+256), fp32 partial out ----------------
__device__ __forceinline__ void mlp1_tile(unsigned short* a_lds, unsigned short* w_lds,
                                          const unsigned short* __restrict__ hcat,
                                          const unsigned short* __restrict__ Wt,
                                          float* __restrict__ pz,
                                          int bm0, int bn0, int kz0, int tid) {
    constexpr int KB = 128;
    const int lane = tid & 63;
    const int wv = tid >> 6;

    f32x4 acc[4] = {};
    const int rA = wv * 16 + (lane & 15);
    const int kq = (lane >> 4) * 8;

    for (int kb = kz0; kb < kz0 + 256; kb += KB) {
        for (int c = tid; c < 64 * KB / 8; c += 256) {
            int r = c >> 4;
            int k = (c & 15) * 8;
            short8 v = *reinterpret_cast<const short8*>(hcat + (size_t)(bm0 + r) * KPAD + kb + k);
            int byte = r * (2 * KB) + ((2 * k) ^ ((r & 7) << 4));
            *reinterpret_cast<short8*>((char*)a_lds + byte) = v;
        }
        for (int c = tid; c < 64 * KB / 8; c += 256) {
            int r = c >> 4;
            int k = (c & 15) * 8;
            short8 v = *reinterpret_cast<const short8*>(Wt + (size_t)(bn0 + r) * KPAD + kb + k);
            int byte = r * (2 * KB) + ((2 * k) ^ ((r & 7) << 4));
            *reinterpret_cast<short8*>((char*)w_lds + byte) = v;
        }
        __syncthreads();
#pragma unroll
        for (int t = 0; t < KB / 32; ++t) {
            const int k0 = t * 32 + kq;
            short8 af = *reinterpret_cast<const short8*>(
                (char*)a_lds + rA * (2 * KB) + ((2 * k0) ^ ((rA & 7) << 4)));
#pragma unroll
            for (int nt = 0; nt < 4; ++nt) {
                const int rW = nt * 16 + (lane & 15);
                short8 bfr = *reinterpret_cast<const short8*>(
                    (char*)w_lds + rW * (2 * KB) + ((2 * k0) ^ ((rW & 7) << 4)));
                acc[nt] = __builtin_amdgcn_mfma_f32_16x16x32_bf16(bfr, af, acc[nt], 0, 0, 0);
            }
        }
        __syncthreads();
    }

    const int row = bm0 + wv * 16 + (lane & 15);
#pragma unroll
    for (int nt = 0; nt < 4; ++nt) {
        int col = bn0 + nt * 16 + (lane >> 4) * 4;
        float4 o; o.x = acc[nt][0]; o.y = acc[nt][1]; o.z = acc[nt][2]; o.w = acc[nt][3];
        *reinterpret_cast<float4*>(pz + (size_t)row * H_F + col) = o;
    }
}

// ---------------- GCN aggregation: 1 node/WAVE, scalar edge loads, ILP-8, NO LDS ----------------
// Pure kernel (no __shared__) -> occupancy 8 blocks/CU (wave-limited), 2048 resident.
// edge norm computed on the fly: rsqrt(cnt[s]+1)*rsqrt(cnt[d]+1)
__global__ __launch_bounds__(256) void k_agg(const unsigned short* __restrict__ hw,
                                             const int* __restrict__ cnt,
                                             const int* __restrict__ srcs_pad,
                                             const float* __restrict__ b,
                                             unsigned short* __restrict__ outp) {
    const int lane = threadIdx.x & 63;
    const int node = __builtin_amdgcn_readfirstlane(blockIdx.x * 4 + (threadIdx.x >> 6));
    const float dd = rsqrtf((float)cnt[node] + 1.0f);
    const unsigned short* rowb = hw + lane * 4;
    const int* sp = srcs_pad + (node << 7);

    float a0, a1, a2, a3;
    {
        const ushort4 sv = *reinterpret_cast<const ushort4*>(hw + (size_t)node * H_F + lane * 4);
        const float4 bv = *reinterpret_cast<const float4*>(b + lane * 4);
        const float ddsq = dd * dd;
        a0 = bf2f(sv.x) * ddsq + bv.x;
        a1 = bf2f(sv.y) * ddsq + bv.y;
        a2 = bf2f(sv.z) * ddsq + bv.z;
        a3 = bf2f(sv.w) * ddsq + bv.w;
    }

    const int e1 = __builtin_amdgcn_readfirstlane(min(cnt[node], DMAX));
    int e = 0;
    for (; e + 8 <= e1; e += 8) {
        ushort4 v[8];
        float w[8];
#pragma unroll
        for (int q = 0; q < 8; ++q) {
            const int s = sp[e + q];                         // uniform -> s_load
            w[q] = rsqrtf((float)cnt[s] + 1.0f) * dd;        // uniform cnt -> s_load
            v[q] = *reinterpret_cast<const ushort4*>(rowb + (size_t)s * H_F);
        }
#pragma unroll
        for (int q = 0; q < 8; ++q) {
            a0 += bf2f(v[q].x) * w[q];
            a1 += bf2f(v[q].y) * w[q];
            a2 += bf2f(v[q].z) * w[q];
            a3 += bf2f(v[q].w) * w[q];
        }
    }
    for (; e < e1; ++e) {
        const int s = sp[e];
        const float w = rsqrtf((float)cnt[s] + 1.0f) * dd;
        const ushort4 v = *reinterpret_cast<const ushort4*>(rowb + (size_t)s * H_F);
        a0 += bf2f(v.x) * w;
        a1 += bf2f(v.y) * w;
        a2 += bf2f(v.z) * w;
        a3 += bf2f(v.w) * w;
    }
    ushort4 o;
    o.x = f2bf(fmaxf(a0, 0.0f));
    o.y = f2bf(fmaxf(a1, 0.0f));
    o.z = f2bf(fmaxf(a2, 0.0f));
    o.w = f2bf(fmaxf(a3, 0.0f));
    *reinterpret_cast<ushort4*>(outp + (size_t)node * H_F + lane * 4) = o;
}

// ---------------- K1: [zero cnt | W1t | W2t | gfp->hcat (x8)] ----------------
__global__ void k_p1(const float* __restrict__ W1, const float* __restrict__ W2,
                     const float* __restrict__ gfp, int* __restrict__ cnt,
                     unsigned short* __restrict__ W1t, unsigned short* __restrict__ W2t,
                     unsigned short* __restrict__ hcat) {
    int w = blockIdx.x;
    if (w < ZB) {
        int i = w * 256 + threadIdx.x;
        if (i < N_NODES) cnt[i] = 0;
        return;
    }
    w -= ZB;
    if (w < W1TB) {
        int i = w * 256 + threadIdx.x;       // < 32768 exactly
        int c = i >> 7, k = i & 127;
        W1t[i] = f2bf(W1[(size_t)k * H_F + c]);
        return;
    }
    w -= W1TB;
    if (w < W2TB) {
        int i = w * 256 + threadIdx.x;       // < 65536 exactly
        int c = i >> 8, k = i & 255;
        W2t[i] = f2bf(W2[(size_t)k * H_F + c]);
        return;
    }
    w -= W2TB;
    {
        int idx = w * 256 + threadIdx.x;     // 0..163839
        int g = idx / 640, k = (idx - g * 640) * 8;
        short8 v = {};
        if (k < FP_F) {                      // FP_F = 5000 = 625*8, chunk-aligned
            const float* src = gfp + (size_t)g * FP_F + k;
            float4 lo = *reinterpret_cast<const float4*>(src);
            float4 hi = *reinterpret_cast<const float4*>(src + 4);
            v[0] = (short)f2bf(lo.x); v[1] = (short)f2bf(lo.y);
            v[2] = (short)f2bf(lo.z); v[3] = (short)f2bf(lo.w);
            v[4] = (short)f2bf(hi.x); v[5] = (short)f2bf(hi.y);
            v[6] = (short)f2bf(hi.z); v[7] = (short)f2bf(hi.w);
        }
        *reinterpret_cast<short8*>(hcat + (size_t)g * KPAD + H_F + k) = v;
    }
}

// ---------------- K2: [gemm1 tiles | fill padded adjacency | Wm1 transpose] ----------------
__global__ __launch_bounds__(256) void k_p2(const float* __restrict__ x,
                                            const unsigned short* __restrict__ W1t,
                                            unsigned short* __restrict__ Abf,
                                            const int* __restrict__ ei,
                                            int* __restrict__ cnt,
                                            int* __restrict__ srcs_pad,
                                            const float* __restrict__ Wm1,
                                            unsigned short* __restrict__ Wt) {
    __shared__ unsigned short a_lds[64 * 128];
    __shared__ unsigned short w_lds[64 * 128];
    int bx = blockIdx.x;
    if (bx < GB) {
        gemm_tile<IN_F, true>(a_lds, w_lds, x, W1t, Abf, (bx % 157) * 64, (bx / 157) * 64,
                              threadIdx.x);
        return;
    }
    bx -= GB;
    if (bx < HB) {
        int e = bx * 256 + threadIdx.x;
        if (e < E_EDGES) {
            int s = ei[e];
            int d = ei[E_EDGES + e];
            int p = atomicAdd(&cnt[d], 1);
            if (p < DMAX) srcs_pad[(d << 7) + p] = s;
        }
        return;
    }
    bx -= HB;
    // Wm1 transpose tile: fp32 [KCAT][256] -> bf16 [256][KPAD]; reuse a_lds as fp32 buf
    float* tbuf = (float*)a_lds;  // 64*65 floats = 16.6 KB < 32 KB of a_lds+w_lds
    const int k0 = (bx % (KPAD / 64)) * 64;
    const int c0 = (bx / (KPAD / 64)) * 64;
    for (int idx = threadIdx.x; idx < 64 * 64; idx += 256) {
        int r = idx >> 6, cc = idx & 63;  // r: k-offset
        int k = k0 + r;
        tbuf[r * 65 + cc] = (k < KCAT) ? Wm1[(size_t)k * H_F + c0 + cc] : 0.0f;
    }
    __syncthreads();
    for (int idx = threadIdx.x; idx < 64 * 64; idx += 256) {
        int r = idx >> 6, kk = idx & 63;  // r: c-offset
        Wt[(size_t)(c0 + r) * KPAD + k0 + kk] = f2bf(tbuf[kk * 65 + r]);
    }
}

// ---------------- K4: [gemm2 tiles | ALL mlp1 z>=1 tiles] (948 blocks, 1 pass) ----------------
__global__ __launch_bounds__(256) void k_p4(const unsigned short* __restrict__ h1,
                                            const unsigned short* __restrict__ W2t,
                                            unsigned short* __restrict__ Abf,
                                            const unsigned short* __restrict__ hcat,
                                            const unsigned short* __restrict__ Wm1t,
                                            float* __restrict__ partial) {
    __shared__ unsigned short a_lds[64 * 128];
    __shared__ unsigned short w_lds[64 * 128];
    int bx = blockIdx.x;
    if (bx < GB) {
        gemm_tile<H_F, false>(a_lds, w_lds, h1, W2t, Abf, (bx % 157) * 64, (bx / 157) * 64,
                              threadIdx.x);
        return;
    }
    bx -= GB;  // 0..319: mlp1 tiles, z in [1, 21)
    const int z = bx / 16 + 1;
    const int r = bx % 16;
    mlp1_tile(a_lds, w_lds, hcat, Wm1t, partial + (size_t)(z - 1) * (G_GRAPHS * H_F),
              (r & 3) * 64, (r >> 2) * 64, z * 256, threadIdx.x);
}

// ---------------- K6: fin = pool + mlp1 z0 + reduce + relu + mlp2 GEMV ----------------
__global__ void k_fin(const unsigned short* __restrict__ h1, const int* __restrict__ batch,
                      const unsigned short* __restrict__ Wm1t,
                      const float* __restrict__ partial, const float* __restrict__ bm1,
                      const float* __restrict__ Wm2, const float* __restrict__ bm2,
                      float* __restrict__ out) {
    __shared__ float m[H_F];
    __shared__ float hrow[H_F];
    const int g = blockIdx.x;
    const int j = threadIdx.x;
    // graph bounds (batch sorted)
    int lo = 0, hi = N_NODES;
    while (lo < hi) { int mm = (lo + hi) >> 1; if (batch[mm] < g) lo = mm + 1; else hi = mm; }
    const int s = lo;
    lo = s; hi = N_NODES;
    while (lo < hi) { int mm = (lo + hi) >> 1; if (batch[mm] < g + 1) lo = mm + 1; else hi = mm; }
    const int e = lo;
    // mean pool column j over rows [s, e)
    float c0 = 0.0f, c1 = 0.0f, c2 = 0.0f, c3 = 0.0f;
    int i = s;
    for (; i + 4 <= e; i += 4) {
        c0 += bf2f(h1[(size_t)(i + 0) * H_F + j]);
        c1 += bf2f(h1[(size_t)(i + 1) * H_F + j]);
        c2 += bf2f(h1[(size_t)(i + 2) * H_F + j]);
        c3 += bf2f(h1[(size_t)(i + 3) * H_F + j]);
    }
    for (; i < e; ++i) c0 += bf2f(h1[(size_t)i * H_F + j]);
    hrow[j] = ((c0 + c1) + (c2 + c3)) / fmaxf((float)(e - s), 1.0f);
    __syncthreads();

    float acc = bm1[j];
    // z=0 contribution: dot(hrow, Wm1t[j, 0:256])
    for (int k = 0; k < H_F; k += 8) {
        short8 wv = *reinterpret_cast<const short8*>(Wm1t + (size_t)j * KPAD + k);
#pragma unroll
        for (int q = 0; q < 8; ++q) acc += hrow[k + q] * bf2f((unsigned short)wv[q]);
    }
    for (int z = 0; z < KZ - 1; ++z)
        acc += partial[((size_t)z * G_GRAPHS + g) * H_F + j];
    m[j] = fmaxf(acc, 0.0f);
    __syncthreads();
    if (j < OUT_F) {
        float a = bm2[j];
        for (int k = 0; k < H_F; ++k) a += m[k] * Wm2[k * OUT_F + j];
        out[g * OUT_F + j] = a;
    }
}

extern "C" void kernel_launch(void* const* d_in, const int* in_sizes, int n_in,
                              void* d_out, int out_size, void* d_ws, size_t ws_size,
                              hipStream_t stream) {
    const float* x       = (const float*)d_in[0];   // [N, IN]
    const int*   ei      = (const int*)d_in[1];     // [2, E]
    const int*   batch   = (const int*)d_in[2];     // [N]
    const float* gfp     = (const float*)d_in[3];   // [G, FP]
    const float* W1      = (const float*)d_in[4];   // [IN, H]
    const float* b1      = (const float*)d_in[5];
    const float* W2      = (const float*)d_in[6];   // [H, H]
    const float* b2      = (const float*)d_in[7];
    const float* Wm1     = (const float*)d_in[8];   // [H+FP, H]
    const float* bm1     = (const float*)d_in[9];
    const float* Wm2     = (const float*)d_in[10];  // [H, OUT]
    const float* bm2     = (const float*)d_in[11];
    float* out = (float*)d_out;                     // [G, OUT]

    // workspace layout (no aliasing)
    unsigned short* W1t  = (unsigned short*)d_ws;              // IN*H bf16
    unsigned short* W2t  = W1t + IN_F * H_F;                   // H*H bf16
    unsigned short* Abf  = W2t + H_F * H_F;                    // N*H bf16
    unsigned short* h1   = Abf + (size_t)N_NODES * H_F;        // N*H bf16
    unsigned short* hcat = h1 + (size_t)N_NODES * H_F;         // G*KPAD bf16
    unsigned short* Wm1t = hcat + (size_t)G_GRAPHS * KPAD;     // H*KPAD bf16
    float* partial = (float*)(Wm1t + (size_t)H_F * KPAD);      // (KZ-1)*G*H f32
    int* cnt      = (int*)(partial + (size_t)(KZ - 1) * G_GRAPHS * H_F);  // N
    int* srcs_pad = cnt + N_NODES;                             // N*DMAX

    // K1: zero cnt | W1t | W2t | gfp->hcat (x8)
    k_p1<<<ZB + W1TB + W2TB + FPB, 256, 0, stream>>>(W1, W2, gfp, cnt, W1t, W2t, hcat);

    // K2: gemm1 | fill padded adjacency | Wm1 transpose
    k_p2<<<GB + HB + WT_TILES, 256, 0, stream>>>(x, W1t, Abf, ei, cnt, srcs_pad, Wm1, Wm1t);

    // K3: agg layer 1 (pure, no LDS -> 8 blocks/CU)
    k_agg<<<AB, 256, 0, stream>>>(Abf, cnt, srcs_pad, b1, h1);

    // K4: gemm2 | all mlp1 z>=1 tiles (948 blocks, single pass)
    k_p4<<<GB + M1B, 256, 0, stream>>>(h1, W2t, Abf, hcat, Wm1t, partial);

    // K5: agg layer 2 (pure)
    k_agg<<<AB, 256, 0, stream>>>(Abf, cnt, srcs_pad, b2, h1);

    // K6: fin (pool + mlp1 z0 + reduce + relu + mlp2)
    k_fin<<<G_GRAPHS, H_F, 0, stream>>>(h1, batch, Wm1t, partial, bm1, Wm2, bm2, out);
}